// Round 3
// baseline (186.503 us; speedup 1.0000x reference)
//
#include <hip/hip_runtime.h>
#include <math.h>

using short8  = __attribute__((ext_vector_type(8))) short;
using ushort8 = __attribute__((ext_vector_type(8))) unsigned short;
using f32x4   = __attribute__((ext_vector_type(4))) float;

constexpr int DIM = 1024, NB = 8, BDIN = 128, EMB = 64, NH = 2, HD = 32;
constexpr float SCALE = 0.17677669529663687f;  // HD^-0.5, folded into wq at prep
constexpr int QP = 1032;   // kernel-B LDS row stride (ushorts): 2064B = 129*16, 16B-aligned b128 rows

__device__ __forceinline__ unsigned short f2bf(float f) {
  unsigned u = __float_as_uint(f);
  u += 0x7fff + ((u >> 16) & 1);  // RNE
  return (unsigned short)(u >> 16);
}
__device__ __forceinline__ float bf2f(unsigned short h) {
  return __uint_as_float((unsigned)h << 16);
}

// ---- prep: weights -> bf16, transposed for MFMA A-operand reads (verified round 2) ----
// ws (ushort): wqT/wkT/wvT [n][e 64][k 128] at 0 / 64K / 128K elems (wq pre-scaled);
//              wfT [n][eo 128][k 64] at 192K elems. Total 512 KB.
__global__ __launch_bounds__(256) void prep_weights(
    const float* __restrict__ wq, const float* __restrict__ wk,
    const float* __restrict__ wv, const float* __restrict__ wf,
    unsigned short* __restrict__ ws)
{
  int gid = blockIdx.x * 256 + threadIdx.x;  // 0..262143
  int m = gid >> 16, r = gid & 65535;
  if (m < 3) {
    const float* w = (m == 0) ? wq : (m == 1) ? wk : wv;
    int n = r >> 13, e = (r >> 7) & 63, k = r & 127;
    float v = w[n * 8192 + k * 64 + e];
    if (m == 0) v *= SCALE;
    ws[m * 65536 + n * 8192 + e * 128 + k] = f2bf(v);
  } else {
    int n = r >> 13, ko = (r >> 6) & 127, e = r & 63;
    ws[3 * 65536 + n * 8192 + ko * 64 + e] = f2bf(wf[n * 8192 + e * 128 + ko]);
  }
}

// ---- Kernel A: block-diagonal QKV GEMM. Zero LDS, zero barriers. ----
// Grid: (tokens/64) * 8.  n = bid & 7, token tile = bid >> 3.  Wave = 16 tokens.
// Writes qkv bf16 into d_out token slots: slot(tok) = out + tok*2048 ushorts,
// layout per token: [m(q,k,v)][n][e=h*32+d]  (1536 ushorts = 3 KB of the 4 KB slot).
__global__ __launch_bounds__(256, 4) void gc_qkv(
    const float* __restrict__ x,
    const unsigned short* __restrict__ wsq,
    const unsigned short* __restrict__ wsk,
    const unsigned short* __restrict__ wsv,
    unsigned short* __restrict__ qkv)
{
  const int tid  = threadIdx.x;
  const int lane = tid & 63;
  const int w    = tid >> 6;
  const int fr   = lane & 15;   // MFMA row/col lane index (token for B/D, e for A)
  const int fg   = lane >> 4;   // MFMA k-group
  const int bid  = blockIdx.x;
  const int n    = bid & 7;
  const long tok = (long)(bid >> 3) * 64 + w * 16 + fr;

  // B-frags: X^T[k][tok], lane col=fr=token, k = s*32 + fg*8 + j
  const float* xp = x + tok * DIM + n * BDIN + fg * 8;
  short8 bfr[4];
  #pragma unroll
  for (int s = 0; s < 4; ++s) {
    float4 a = *reinterpret_cast<const float4*>(xp + s * 32);
    float4 b = *reinterpret_cast<const float4*>(xp + s * 32 + 4);
    short8 v;
    v[0] = (short)f2bf(a.x); v[1] = (short)f2bf(a.y);
    v[2] = (short)f2bf(a.z); v[3] = (short)f2bf(a.w);
    v[4] = (short)f2bf(b.x); v[5] = (short)f2bf(b.y);
    v[6] = (short)f2bf(b.z); v[7] = (short)f2bf(b.w);
    bfr[s] = v;
  }

  #pragma unroll
  for (int et = 0; et < 12; ++et) {          // 12 e-tiles: m = et>>2, e0 = (et&3)*16
    const int m  = et >> 2;
    const int e0 = (et & 3) * 16;
    const unsigned short* wb = (m == 0) ? wsq : (m == 1) ? wsk : wsv;
    const unsigned short* wp = wb + n * 8192 + (e0 + fr) * 128 + fg * 8;
    f32x4 acc = {0.f, 0.f, 0.f, 0.f};
    #pragma unroll
    for (int s = 0; s < 4; ++s) {
      short8 af = *reinterpret_cast<const short8*>(wp + s * 32);
      acc = __builtin_amdgcn_mfma_f32_16x16x32_bf16(af, bfr[s], acc, 0, 0, 0);
    }
    // D: lane holds D[e = e0 + fg*4 + r][tok = fr]
    ushort4 d4;
    d4.x = f2bf(acc[0]); d4.y = f2bf(acc[1]); d4.z = f2bf(acc[2]); d4.w = f2bf(acc[3]);
    *reinterpret_cast<ushort4*>(qkv + tok * 2048 + m * 512 + n * 64 + e0 + fg * 4) = d4;
  }
}

// ---- Kernel B: attention + out-projection. 16 tokens/WG, time-shared 33 KB LDS. ----
__global__ __launch_bounds__(256, 4) void gc_attn(
    const unsigned short* __restrict__ qkv,
    const unsigned short* __restrict__ wsf,
    float* __restrict__ out)
{
  __shared__ __align__(16) unsigned short sq[16][QP];  // [0..511]=q then v; [512..1023]=k then attn_out
  __shared__ float spT[16][NH][NB][NB + 1];            // P^T: [t][h][m][n]

  const int tid  = threadIdx.x;
  const int lane = tid & 63;
  const int w    = tid >> 6;
  const int fr   = lane & 15;
  const int fg   = lane >> 4;
  const long tok0 = (long)blockIdx.x * 16;
  const unsigned short* slot = qkv + tok0 * 2048;

  // ---- stage q|k (first 2048B of each token slot) ----
  {
    const int t = tid >> 4, j = tid & 15;
    #pragma unroll
    for (int c = 0; c < 8; ++c)
      *reinterpret_cast<ushort8*>(&sq[t][c * 128 + j * 8]) =
          *reinterpret_cast<const ushort8*>(slot + t * 2048 + c * 128 + j * 8);
  }
  // issue v loads early (T14): consumed after phase B's barrier
  ushort8 vreg[4];
  {
    const int t = tid >> 4, j = tid & 15;
    #pragma unroll
    for (int c = 0; c < 4; ++c)
      vreg[c] = *reinterpret_cast<const ushort8*>(slot + t * 2048 + 1024 + c * 128 + j * 8);
  }
  __syncthreads();

  // ---- phase B: scores + softmax; thread = (t, h, nq) over all 256 ----
  {
    const int t  = tid >> 4;
    const int h  = (tid >> 3) & 1;
    const int nq = tid & 7;
    const unsigned short* qrow = &sq[t][nq * 64 + h * 32];
    float q[HD];
    #pragma unroll
    for (int cc = 0; cc < 4; ++cc) {       // rotate by nq: breaks bank conflict
      int c = (cc + nq) & 3;
      short8 qv = *reinterpret_cast<const short8*>(qrow + c * 8);
      #pragma unroll
      for (int j = 0; j < 8; ++j) q[c * 8 + j] = bf2f((unsigned short)qv[j]);
    }
    float sc[NB];
    #pragma unroll
    for (int m = 0; m < NB; ++m) {
      const unsigned short* krow = &sq[t][512 + m * 64 + h * 32];  // broadcast across nq
      float a = 0.f;
      #pragma unroll
      for (int c = 0; c < 4; ++c) {
        short8 kv = *reinterpret_cast<const short8*>(krow + c * 8);
        #pragma unroll
        for (int j = 0; j < 8; ++j) a = fmaf(q[c * 8 + j], bf2f((unsigned short)kv[j]), a);
      }
      sc[m] = a;
    }
    float mx = sc[0];
    #pragma unroll
    for (int m = 1; m < NB; ++m) mx = fmaxf(mx, sc[m]);
    float sum = 0.f;
    #pragma unroll
    for (int m = 0; m < NB; ++m) { sc[m] = __expf(sc[m] - mx); sum += sc[m]; }
    const float inv = 1.f / sum;
    #pragma unroll
    for (int m = 0; m < NB; ++m) spT[t][h][m][nq] = sc[m] * inv;
  }
  __syncthreads();                         // q dead; write v over it
  {
    const int t = tid >> 4, j = tid & 15;
    #pragma unroll
    for (int c = 0; c < 4; ++c)
      *reinterpret_cast<ushort8*>(&sq[t][c * 128 + j * 8]) = vreg[c];
  }
  __syncthreads();

  // ---- phase C: attn_out = P @ V -> overwrite k region; thread = (t, h, g) ----
  {
    const int t = tid >> 4;
    const int h = (tid >> 3) & 1;
    const int g = tid & 7;
    float acc[NB][4] = {};
    #pragma unroll
    for (int m = 0; m < NB; ++m) {
      ushort4 vv = *reinterpret_cast<const ushort4*>(&sq[t][m * 64 + h * 32 + g * 4]);
      float v0 = bf2f(vv.x), v1 = bf2f(vv.y), v2 = bf2f(vv.z), v3 = bf2f(vv.w);
      const float* pr = spT[t][h][m];
      #pragma unroll
      for (int n = 0; n < NB; ++n) {
        float p = pr[n];
        acc[n][0] = fmaf(p, v0, acc[n][0]);
        acc[n][1] = fmaf(p, v1, acc[n][1]);
        acc[n][2] = fmaf(p, v2, acc[n][2]);
        acc[n][3] = fmaf(p, v3, acc[n][3]);
      }
    }
    #pragma unroll
    for (int n = 0; n < NB; ++n) {
      ushort4 b;
      b.x = f2bf(acc[n][0]); b.y = f2bf(acc[n][1]);
      b.z = f2bf(acc[n][2]); b.w = f2bf(acc[n][3]);
      *reinterpret_cast<ushort4*>(&sq[t][512 + n * 64 + h * 32 + g * 4]) = b;
    }
  }
  __syncthreads();

  // ---- phase D: out = attn_out @ wf via MFMA; wave w owns n = w*2 + bi ----
  {
    #pragma unroll
    for (int bi = 0; bi < 2; ++bi) {
      int n = w * 2 + bi;
      short8 bfr[2];                       // attn_out^T frags, shared across 8 e-tiles
      #pragma unroll
      for (int s = 0; s < 2; ++s)
        bfr[s] = *reinterpret_cast<const short8*>(&sq[fr][512 + n * 64 + s * 32 + fg * 8]);
      #pragma unroll
      for (int et = 0; et < 8; ++et) {
        const unsigned short* wp = wsf + n * 8192 + (et * 16 + fr) * 64 + fg * 8;
        f32x4 acc = {0.f, 0.f, 0.f, 0.f};
        #pragma unroll
        for (int s = 0; s < 2; ++s) {
          short8 af = *reinterpret_cast<const short8*>(wp + s * 32);
          acc = __builtin_amdgcn_mfma_f32_16x16x32_bf16(af, bfr[s], acc, 0, 0, 0);
        }
        float4 o; o.x = acc[0]; o.y = acc[1]; o.z = acc[2]; o.w = acc[3];
        *reinterpret_cast<float4*>(out + (tok0 + fr) * DIM + n * BDIN + et * 16 + fg * 4) = o;
      }
    }
  }
}

extern "C" void kernel_launch(void* const* d_in, const int* in_sizes, int n_in,
                              void* d_out, int out_size, void* d_ws, size_t ws_size,
                              hipStream_t stream) {
  const float* x  = (const float*)d_in[0];
  const float* wq = (const float*)d_in[1];
  const float* wk = (const float*)d_in[2];
  const float* wv = (const float*)d_in[3];
  const float* wf = (const float*)d_in[4];
  float* out = (float*)d_out;
  unsigned short* ws = (unsigned short*)d_ws;
  unsigned short* qkv = (unsigned short*)d_out;   // qkv bf16 lives inside out slots

  prep_weights<<<dim3(1024), dim3(256), 0, stream>>>(wq, wk, wv, wf, ws);

  const int tokens = in_sizes[0] / DIM;   // 32768
  gc_qkv<<<dim3((tokens / 64) * 8), dim3(256), 0, stream>>>(
      x, ws, ws + 65536, ws + 131072, qkv);
  gc_attn<<<dim3(tokens / 16), dim3(256), 0, stream>>>(qkv, ws + 196608, out);
}

// Round 4
// 131.204 us; speedup vs baseline: 1.4215x; 1.4215x over previous
//
#include <hip/hip_runtime.h>
#include <math.h>

using short8  = __attribute__((ext_vector_type(8))) short;
using ushort8 = __attribute__((ext_vector_type(8))) unsigned short;
using f32x4   = __attribute__((ext_vector_type(4))) float;

constexpr int DIM = 1024, NB = 8, BDIN = 128, EMB = 64, NH = 2, HD = 32;
constexpr float SCALE = 0.17677669529663687f;  // HD^-0.5, folded into wq at prep
constexpr int QP  = 1032;  // kernel-B LDS row stride (ushorts)
constexpr int SXW = 136;   // kernel-A x-tile row stride (ushorts): 272B -> 4-bank row step

__device__ __forceinline__ unsigned short f2bf(float f) {
  unsigned u = __float_as_uint(f);
  u += 0x7fff + ((u >> 16) & 1);  // RNE
  return (unsigned short)(u >> 16);
}
__device__ __forceinline__ float bf2f(unsigned short h) {
  return __uint_as_float((unsigned)h << 16);
}

// ---- prep: weights -> bf16, transposed for MFMA A-operand reads (verified) ----
// ws (ushort): wqT/wkT/wvT [n][e 64][k 128] at 0 / 64K / 128K elems (wq pre-scaled);
//              wfT [n][eo 128][k 64] at 192K elems. Total 512 KB.
__global__ __launch_bounds__(256) void prep_weights(
    const float* __restrict__ wq, const float* __restrict__ wk,
    const float* __restrict__ wv, const float* __restrict__ wf,
    unsigned short* __restrict__ ws)
{
  int gid = blockIdx.x * 256 + threadIdx.x;  // 0..262143
  int m = gid >> 16, r = gid & 65535;
  if (m < 3) {
    const float* w = (m == 0) ? wq : (m == 1) ? wk : wv;
    int n = r >> 13, e = (r >> 7) & 63, k = r & 127;
    float v = w[n * 8192 + k * 64 + e];
    if (m == 0) v *= SCALE;
    ws[m * 65536 + n * 8192 + e * 128 + k] = f2bf(v);
  } else {
    int n = r >> 13, ko = (r >> 6) & 127, e = r & 63;
    ws[3 * 65536 + n * 8192 + ko * 64 + e] = f2bf(wf[n * 8192 + e * 128 + ko]);
  }
}

// ---- Kernel A: block-diagonal QKV GEMM, LDS-staged x + register-resident weights ----
// Grid: (tokens/64) * 8.  n = bid & 7, token tile (64) = bid >> 3.
// qkv layout per token (in d_out slots, 2048 ushorts): [m(q,k,v)][n][e=h*32+d].
__global__ __launch_bounds__(256, 3) void gc_qkv(
    const float* __restrict__ x,
    const unsigned short* __restrict__ wsq,
    const unsigned short* __restrict__ wsk,
    const unsigned short* __restrict__ wsv,
    unsigned short* __restrict__ qkv)
{
  __shared__ __align__(16) unsigned short sx[64][SXW];   // 17.4 KB

  const int tid  = threadIdx.x;
  const int lane = tid & 63;
  const int w    = tid >> 6;
  const int fr   = lane & 15;   // MFMA row/col lane index
  const int fg   = lane >> 4;   // MFMA k-group
  const int bid  = blockIdx.x;
  const int n    = bid & 7;
  const long tok0 = (long)(bid >> 3) * 64;

  // -- issue x loads: 4 iters x 2 contiguous float4/thread, fully coalesced --
  float4 xa[4], xb[4];
  const float* xbase = x + tok0 * DIM + n * BDIN;
  #pragma unroll
  for (int jj = 0; jj < 4; ++jj) {
    int p  = tid + 256 * jj;        // pair index 0..1023
    int r  = p >> 4;                // token row 0..63
    int c8 = p & 15;                // 8-float chunk in row
    const float* src = xbase + (long)r * DIM + c8 * 8;
    xa[jj] = *reinterpret_cast<const float4*>(src);
    xb[jj] = *reinterpret_cast<const float4*>(src + 4);
  }

  // -- weight frags for this wave's 3 e-tiles: 12 independent L2 loads, live in regs --
  short8 wfrag[3][4];
  #pragma unroll
  for (int i = 0; i < 3; ++i) {
    int et = w * 3 + i;             // 0..11
    int m  = et >> 2;
    int e0 = (et & 3) * 16;
    const unsigned short* wb = (m == 0) ? wsq : (m == 1) ? wsk : wsv;
    const unsigned short* wp = wb + n * 8192 + (e0 + fr) * 128 + fg * 8;
    #pragma unroll
    for (int s = 0; s < 4; ++s)
      wfrag[i][s] = *reinterpret_cast<const short8*>(wp + s * 32);
  }

  // -- convert x to bf16, write LDS --
  #pragma unroll
  for (int jj = 0; jj < 4; ++jj) {
    int p  = tid + 256 * jj;
    int r  = p >> 4;
    int c8 = p & 15;
    ushort8 v;
    v[0] = f2bf(xa[jj].x); v[1] = f2bf(xa[jj].y);
    v[2] = f2bf(xa[jj].z); v[3] = f2bf(xa[jj].w);
    v[4] = f2bf(xb[jj].x); v[5] = f2bf(xb[jj].y);
    v[6] = f2bf(xb[jj].z); v[7] = f2bf(xb[jj].w);
    *reinterpret_cast<ushort8*>(&sx[r][c8 * 8]) = v;
  }
  __syncthreads();

  // -- 4 token sub-tiles: ds_read B-frags, MFMA against register weights, store --
  #pragma unroll
  for (int tt = 0; tt < 4; ++tt) {
    short8 bfr[4];
    #pragma unroll
    for (int s = 0; s < 4; ++s)
      bfr[s] = *reinterpret_cast<const short8*>(&sx[tt * 16 + fr][s * 32 + fg * 8]);
    const long tok = tok0 + tt * 16 + fr;
    #pragma unroll
    for (int i = 0; i < 3; ++i) {
      int et = w * 3 + i;
      int m  = et >> 2;
      int e0 = (et & 3) * 16;
      f32x4 acc = {0.f, 0.f, 0.f, 0.f};
      #pragma unroll
      for (int s = 0; s < 4; ++s)
        acc = __builtin_amdgcn_mfma_f32_16x16x32_bf16(wfrag[i][s], bfr[s], acc, 0, 0, 0);
      ushort4 d4;
      d4.x = f2bf(acc[0]); d4.y = f2bf(acc[1]);
      d4.z = f2bf(acc[2]); d4.w = f2bf(acc[3]);
      *reinterpret_cast<ushort4*>(qkv + tok * 2048 + m * 512 + n * 64 + e0 + fg * 4) = d4;
    }
  }
}

// ---- Kernel B: attention + out-projection (unchanged from round 3, near floor) ----
__global__ __launch_bounds__(256, 4) void gc_attn(
    const unsigned short* __restrict__ qkv,
    const unsigned short* __restrict__ wsf,
    float* __restrict__ out)
{
  __shared__ __align__(16) unsigned short sq[16][QP];  // [0..511]=q then v; [512..1023]=k then attn_out
  __shared__ float spT[16][NH][NB][NB + 1];            // P^T: [t][h][m][n]

  const int tid  = threadIdx.x;
  const int lane = tid & 63;
  const int w    = tid >> 6;
  const int fr   = lane & 15;
  const int fg   = lane >> 4;
  const long tok0 = (long)blockIdx.x * 16;
  const unsigned short* slot = qkv + tok0 * 2048;

  // stage q|k
  {
    const int t = tid >> 4, j = tid & 15;
    #pragma unroll
    for (int c = 0; c < 8; ++c)
      *reinterpret_cast<ushort8*>(&sq[t][c * 128 + j * 8]) =
          *reinterpret_cast<const ushort8*>(slot + t * 2048 + c * 128 + j * 8);
  }
  // issue v loads early; consumed after phase-B barrier
  ushort8 vreg[4];
  {
    const int t = tid >> 4, j = tid & 15;
    #pragma unroll
    for (int c = 0; c < 4; ++c)
      vreg[c] = *reinterpret_cast<const ushort8*>(slot + t * 2048 + 1024 + c * 128 + j * 8);
  }
  __syncthreads();

  // phase B: scores + softmax; thread = (t, h, nq)
  {
    const int t  = tid >> 4;
    const int h  = (tid >> 3) & 1;
    const int nq = tid & 7;
    const unsigned short* qrow = &sq[t][nq * 64 + h * 32];
    float q[HD];
    #pragma unroll
    for (int cc = 0; cc < 4; ++cc) {
      int c = (cc + nq) & 3;
      short8 qv = *reinterpret_cast<const short8*>(qrow + c * 8);
      #pragma unroll
      for (int j = 0; j < 8; ++j) q[c * 8 + j] = bf2f((unsigned short)qv[j]);
    }
    float sc[NB];
    #pragma unroll
    for (int m = 0; m < NB; ++m) {
      const unsigned short* krow = &sq[t][512 + m * 64 + h * 32];
      float a = 0.f;
      #pragma unroll
      for (int c = 0; c < 4; ++c) {
        short8 kv = *reinterpret_cast<const short8*>(krow + c * 8);
        #pragma unroll
        for (int j = 0; j < 8; ++j) a = fmaf(q[c * 8 + j], bf2f((unsigned short)kv[j]), a);
      }
      sc[m] = a;
    }
    float mx = sc[0];
    #pragma unroll
    for (int m = 1; m < NB; ++m) mx = fmaxf(mx, sc[m]);
    float sum = 0.f;
    #pragma unroll
    for (int m = 0; m < NB; ++m) { sc[m] = __expf(sc[m] - mx); sum += sc[m]; }
    const float inv = 1.f / sum;
    #pragma unroll
    for (int m = 0; m < NB; ++m) spT[t][h][m][nq] = sc[m] * inv;
  }
  __syncthreads();                 // q dead; overwrite with v
  {
    const int t = tid >> 4, j = tid & 15;
    #pragma unroll
    for (int c = 0; c < 4; ++c)
      *reinterpret_cast<ushort8*>(&sq[t][c * 128 + j * 8]) = vreg[c];
  }
  __syncthreads();

  // phase C: attn_out = P @ V -> overwrite k region
  {
    const int t = tid >> 4;
    const int h = (tid >> 3) & 1;
    const int g = tid & 7;
    float acc[NB][4] = {};
    #pragma unroll
    for (int m = 0; m < NB; ++m) {
      ushort4 vv = *reinterpret_cast<const ushort4*>(&sq[t][m * 64 + h * 32 + g * 4]);
      float v0 = bf2f(vv.x), v1 = bf2f(vv.y), v2 = bf2f(vv.z), v3 = bf2f(vv.w);
      const float* pr = spT[t][h][m];
      #pragma unroll
      for (int nn = 0; nn < NB; ++nn) {
        float p = pr[nn];
        acc[nn][0] = fmaf(p, v0, acc[nn][0]);
        acc[nn][1] = fmaf(p, v1, acc[nn][1]);
        acc[nn][2] = fmaf(p, v2, acc[nn][2]);
        acc[nn][3] = fmaf(p, v3, acc[nn][3]);
      }
    }
    #pragma unroll
    for (int nn = 0; nn < NB; ++nn) {
      ushort4 b;
      b.x = f2bf(acc[nn][0]); b.y = f2bf(acc[nn][1]);
      b.z = f2bf(acc[nn][2]); b.w = f2bf(acc[nn][3]);
      *reinterpret_cast<ushort4*>(&sq[t][512 + nn * 64 + h * 32 + g * 4]) = b;
    }
  }
  __syncthreads();

  // phase D: out = attn_out @ wf via MFMA
  {
    #pragma unroll
    for (int bi = 0; bi < 2; ++bi) {
      int nn = w * 2 + bi;
      short8 bfr[2];
      #pragma unroll
      for (int s = 0; s < 2; ++s)
        bfr[s] = *reinterpret_cast<const short8*>(&sq[fr][512 + nn * 64 + s * 32 + fg * 8]);
      #pragma unroll
      for (int et = 0; et < 8; ++et) {
        const unsigned short* wp = wsf + nn * 8192 + (et * 16 + fr) * 64 + fg * 8;
        f32x4 acc = {0.f, 0.f, 0.f, 0.f};
        #pragma unroll
        for (int s = 0; s < 2; ++s) {
          short8 af = *reinterpret_cast<const short8*>(wp + s * 32);
          acc = __builtin_amdgcn_mfma_f32_16x16x32_bf16(af, bfr[s], acc, 0, 0, 0);
        }
        float4 o; o.x = acc[0]; o.y = acc[1]; o.z = acc[2]; o.w = acc[3];
        *reinterpret_cast<float4*>(out + (tok0 + fr) * DIM + nn * BDIN + et * 16 + fg * 4) = o;
      }
    }
  }
}

extern "C" void kernel_launch(void* const* d_in, const int* in_sizes, int n_in,
                              void* d_out, int out_size, void* d_ws, size_t ws_size,
                              hipStream_t stream) {
  const float* x  = (const float*)d_in[0];
  const float* wq = (const float*)d_in[1];
  const float* wk = (const float*)d_in[2];
  const float* wv = (const float*)d_in[3];
  const float* wf = (const float*)d_in[4];
  float* out = (float*)d_out;
  unsigned short* ws = (unsigned short*)d_ws;
  unsigned short* qkv = (unsigned short*)d_out;   // qkv bf16 lives inside out slots

  prep_weights<<<dim3(1024), dim3(256), 0, stream>>>(wq, wk, wv, wf, ws);

  const int tokens = in_sizes[0] / DIM;   // 32768
  gc_qkv<<<dim3((tokens / 64) * 8), dim3(256), 0, stream>>>(
      x, ws, ws + 65536, ws + 131072, qkv);
  gc_attn<<<dim3(tokens / 16), dim3(256), 0, stream>>>(qkv, ws + 196608, out);
}

// Round 5
// 113.528 us; speedup vs baseline: 1.6428x; 1.1557x over previous
//
#include <hip/hip_runtime.h>
#include <math.h>

using short8  = __attribute__((ext_vector_type(8))) short;
using ushort8 = __attribute__((ext_vector_type(8))) unsigned short;
using f32x4   = __attribute__((ext_vector_type(4))) float;

constexpr int DIM = 1024, NB = 8, NH = 2, HD = 32;
constexpr float SCALE = 0.17677669529663687f;  // HD^-0.5, folded into wq at prep
constexpr int SXW = 1032;   // x-tile row stride (ushorts): 2064B -> 4-bank row step, 16B-aligned
constexpr int SQW = 1544;   // qkv row stride (ushorts): 3088B -> 4-bank row step, 16B-aligned

__device__ __forceinline__ unsigned short f2bf(float f) {
  unsigned u = __float_as_uint(f);
  u += 0x7fff + ((u >> 16) & 1);  // RNE
  return (unsigned short)(u >> 16);
}
__device__ __forceinline__ float bf2f(unsigned short h) {
  return __uint_as_float((unsigned)h << 16);
}

// ---- prep: weights -> bf16 in MFMA *fragment order* ----
// QKV tiles: idx t = met*8+n (met = m*4+et, m in {q,k,v}, et = 16-e subtile), each 2048 ush:
//   offset = s*512 + lane*8 + z  <->  A[e = et*16 + (lane&15)][k = s*32 + (lane>>4)*8 + z]
// wf tiles at 196608: idx t = n*8+et, each 1024 ush (s in 0..1), same fragment rule with
//   A[ko = et*16 + fr][k(=emb) = s*32 + fg*8 + z].
// Wave loads become single fully-coalesced 1KB reads.
__global__ __launch_bounds__(256) void prep_weights(
    const float* __restrict__ wq, const float* __restrict__ wk,
    const float* __restrict__ wv, const float* __restrict__ wf,
    unsigned short* __restrict__ ws)
{
  int gid = blockIdx.x * 256 + threadIdx.x;   // 0..262143
  if (gid < 196608) {
    int t = gid >> 11, r = gid & 2047;
    int s = r >> 9, l = (r >> 3) & 63, z = r & 7;
    int met = t >> 3, n = t & 7, m = met >> 2, et = met & 3;
    int fr = l & 15, fg = l >> 4;
    int e = et * 16 + fr, k = s * 32 + fg * 8 + z;
    const float* w = (m == 0) ? wq : (m == 1) ? wk : wv;
    float v = w[n * 8192 + k * 64 + e];
    if (m == 0) v *= SCALE;
    ws[gid] = f2bf(v);
  } else {
    int g2 = gid - 196608;
    int t = g2 >> 10, r = g2 & 1023;
    int s = r >> 9, l = (r >> 3) & 63, z = r & 7;
    int n = t >> 3, et = t & 7;
    int fr = l & 15, fg = l >> 4;
    int eo = et * 16 + fr, k = s * 32 + fg * 8 + z;
    ws[gid] = f2bf(wf[n * 8192 + k * 128 + eo]);
  }
}

// ---- fused kernel: 16 tokens/WG, 512 threads, whole layer in one pass ----
__global__ __launch_bounds__(512, 4) void gc_fused(
    const float* __restrict__ x,
    const unsigned short* __restrict__ wsw,   // 96 qkv tiles [2048]
    const unsigned short* __restrict__ wsf,   // 64 wf tiles  [1024]
    float* __restrict__ out)
{
  // smem overlays: phase A reads x at rows [r*SXW]; after barrier qkv rows [t*SQW]
  // regions: q [0,512) | k [512,1024) | v [1024,1536); attn_out overwrites q.
  __shared__ __align__(16) unsigned short smem[16 * SQW];   // 49.4 KB
  __shared__ float spT[16][NH][NB][NB + 1];                 // 9.2 KB

  const int tid  = threadIdx.x;
  const int lane = tid & 63;
  const int w    = tid >> 6;
  const int fr   = lane & 15;
  const int fg   = lane >> 4;
  const long tok0 = (long)blockIdx.x * 16;

  // ---- stage x -> bf16 LDS (fully coalesced 2KB/wave reads) ----
  {
    const float* xb = x + tok0 * DIM;
    float4 xa[4], xc[4];
    #pragma unroll
    for (int jj = 0; jj < 4; ++jj) {
      int chunk = tid + 512 * jj;                  // 32B chunks, 128 per token row
      const float* src = xb + (long)(chunk >> 7) * DIM + (chunk & 127) * 8;
      xa[jj] = *reinterpret_cast<const float4*>(src);
      xc[jj] = *reinterpret_cast<const float4*>(src + 4);
    }
    #pragma unroll
    for (int jj = 0; jj < 4; ++jj) {
      int chunk = tid + 512 * jj;
      ushort8 v;
      v[0] = f2bf(xa[jj].x); v[1] = f2bf(xa[jj].y);
      v[2] = f2bf(xa[jj].z); v[3] = f2bf(xa[jj].w);
      v[4] = f2bf(xc[jj].x); v[5] = f2bf(xc[jj].y);
      v[6] = f2bf(xc[jj].z); v[7] = f2bf(xc[jj].w);
      *reinterpret_cast<ushort8*>(&smem[(chunk >> 7) * SXW + (chunk & 127) * 8]) = v;
    }
  }
  __syncthreads();

  // ---- phase A: 96 (m,et,n) QKV tiles over 8 waves, 12 each, dbuf weight prefetch ----
  ushort4 qreg[12];
  {
    short8 wfr[2][4];
    {
      const unsigned short* wp0 = wsw + (w * 12) * 2048 + lane * 8;
      #pragma unroll
      for (int s = 0; s < 4; ++s)
        wfr[0][s] = *reinterpret_cast<const short8*>(wp0 + s * 512);
    }
    #pragma unroll
    for (int j = 0; j < 12; ++j) {
      const int cc = w * 12 + j;
      const int n  = cc & 7;
      if (j < 11) {                                // prefetch next tile's frags
        const unsigned short* wpn = wsw + (cc + 1) * 2048 + lane * 8;
        #pragma unroll
        for (int s = 0; s < 4; ++s)
          wfr[(j + 1) & 1][s] = *reinterpret_cast<const short8*>(wpn + s * 512);
      }
      short8 bfr[4];
      #pragma unroll
      for (int s = 0; s < 4; ++s)
        bfr[s] = *reinterpret_cast<const short8*>(&smem[fr * SXW + n * 128 + s * 32 + fg * 8]);
      f32x4 acc = {0.f, 0.f, 0.f, 0.f};
      #pragma unroll
      for (int s = 0; s < 4; ++s)
        acc = __builtin_amdgcn_mfma_f32_16x16x32_bf16(wfr[j & 1][s], bfr[s], acc, 0, 0, 0);
      ushort4 d4;
      d4.x = f2bf(acc[0]); d4.y = f2bf(acc[1]);
      d4.z = f2bf(acc[2]); d4.w = f2bf(acc[3]);
      qreg[j] = d4;
    }
  }
  __syncthreads();                                 // all x reads done; x region dies

  // ---- write qkv frags to LDS (overlays x) ----
  {
    #pragma unroll
    for (int j = 0; j < 12; ++j) {
      const int cc = w * 12 + j;
      const int met = cc >> 3, n = cc & 7;
      const int m = met >> 2, e0 = (met & 3) * 16;
      *reinterpret_cast<ushort4*>(&smem[fr * SQW + m * 512 + n * 64 + e0 + fg * 4]) = qreg[j];
    }
  }
  __syncthreads();

  // ---- phase B: scores + softmax; 256 threads = (t, h, nq) ----
  if (tid < 256) {
    const int t  = tid >> 4;
    const int h  = (tid >> 3) & 1;
    const int nq = tid & 7;
    const unsigned short* qrow = &smem[t * SQW + nq * 64 + h * 32];
    float q[HD];
    #pragma unroll
    for (int cc = 0; cc < 4; ++cc) {               // rotate by nq: spreads bank groups
      int c = (cc + nq) & 3;
      short8 qv = *reinterpret_cast<const short8*>(qrow + c * 8);
      #pragma unroll
      for (int j = 0; j < 8; ++j) q[c * 8 + j] = bf2f((unsigned short)qv[j]);
    }
    float sc[NB];
    #pragma unroll
    for (int m = 0; m < NB; ++m) {
      const unsigned short* krow = &smem[t * SQW + 512 + m * 64 + h * 32];  // broadcast
      float a = 0.f;
      #pragma unroll
      for (int c = 0; c < 4; ++c) {
        short8 kv = *reinterpret_cast<const short8*>(krow + c * 8);
        #pragma unroll
        for (int j = 0; j < 8; ++j) a = fmaf(q[c * 8 + j], bf2f((unsigned short)kv[j]), a);
      }
      sc[m] = a;
    }
    float mx = sc[0];
    #pragma unroll
    for (int m = 1; m < NB; ++m) mx = fmaxf(mx, sc[m]);
    float sum = 0.f;
    #pragma unroll
    for (int m = 0; m < NB; ++m) { sc[m] = __expf(sc[m] - mx); sum += sc[m]; }
    const float inv = 1.f / sum;
    #pragma unroll
    for (int m = 0; m < NB; ++m) spT[t][h][m][nq] = sc[m] * inv;
  }
  __syncthreads();                                 // q reads done; P visible

  // ---- phase C: attn_out = P @ V -> overwrite q region; 256 threads = (t, h, g) ----
  if (tid < 256) {
    const int t = tid >> 4;
    const int h = (tid >> 3) & 1;
    const int g = tid & 7;
    float acc[NB][4] = {};
    #pragma unroll
    for (int m = 0; m < NB; ++m) {
      ushort4 vv = *reinterpret_cast<const ushort4*>(
          &smem[t * SQW + 1024 + m * 64 + h * 32 + g * 4]);
      float v0 = bf2f(vv.x), v1 = bf2f(vv.y), v2 = bf2f(vv.z), v3 = bf2f(vv.w);
      const float* pr = spT[t][h][m];
      #pragma unroll
      for (int nn = 0; nn < NB; ++nn) {
        float p = pr[nn];
        acc[nn][0] = fmaf(p, v0, acc[nn][0]);
        acc[nn][1] = fmaf(p, v1, acc[nn][1]);
        acc[nn][2] = fmaf(p, v2, acc[nn][2]);
        acc[nn][3] = fmaf(p, v3, acc[nn][3]);
      }
    }
    #pragma unroll
    for (int nn = 0; nn < NB; ++nn) {
      ushort4 b;
      b.x = f2bf(acc[nn][0]); b.y = f2bf(acc[nn][1]);
      b.z = f2bf(acc[nn][2]); b.w = f2bf(acc[nn][3]);
      *reinterpret_cast<ushort4*>(&smem[t * SQW + nn * 64 + h * 32 + g * 4]) = b;
    }
  }
  __syncthreads();

  // ---- phase D: out = attn_out @ wf; wave w owns block n = w ----
  {
    const int n = w;
    short8 bfr[2];
    #pragma unroll
    for (int s = 0; s < 2; ++s)
      bfr[s] = *reinterpret_cast<const short8*>(&smem[fr * SQW + n * 64 + s * 32 + fg * 8]);
    #pragma unroll
    for (int et = 0; et < 8; ++et) {
      const unsigned short* wp = wsf + (n * 8 + et) * 1024 + lane * 8;
      f32x4 acc = {0.f, 0.f, 0.f, 0.f};
      #pragma unroll
      for (int s = 0; s < 2; ++s) {
        short8 af = *reinterpret_cast<const short8*>(wp + s * 512);
        acc = __builtin_amdgcn_mfma_f32_16x16x32_bf16(af, bfr[s], acc, 0, 0, 0);
      }
      float4 o; o.x = acc[0]; o.y = acc[1]; o.z = acc[2]; o.w = acc[3];
      *reinterpret_cast<float4*>(out + (tok0 + fr) * DIM + n * 128 + et * 16 + fg * 4) = o;
    }
  }
}

extern "C" void kernel_launch(void* const* d_in, const int* in_sizes, int n_in,
                              void* d_out, int out_size, void* d_ws, size_t ws_size,
                              hipStream_t stream) {
  const float* x  = (const float*)d_in[0];
  const float* wq = (const float*)d_in[1];
  const float* wk = (const float*)d_in[2];
  const float* wv = (const float*)d_in[3];
  const float* wf = (const float*)d_in[4];
  float* out = (float*)d_out;
  unsigned short* ws = (unsigned short*)d_ws;

  prep_weights<<<dim3(1024), dim3(256), 0, stream>>>(wq, wk, wv, wf, ws);

  const int tokens = in_sizes[0] / DIM;   // 32768
  gc_fused<<<dim3(tokens / 16), dim3(512), 0, stream>>>(x, ws, ws + 196608, out);
}

// Round 7
// 88.210 us; speedup vs baseline: 2.1143x; 1.2870x over previous
//
#include <hip/hip_runtime.h>
#include <math.h>

using short8  = __attribute__((ext_vector_type(8))) short;
using ushort8 = __attribute__((ext_vector_type(8))) unsigned short;
using f32x4   = __attribute__((ext_vector_type(4))) float;

constexpr int DIM = 1024, NB = 8, NH = 2, HD = 32;
constexpr float SCALE = 0.17677669529663687f;  // HD^-0.5, folded into wq at prep
constexpr int SXW = 1032;   // x-tile row stride (ushorts): 2064B -> 4-bank row step
constexpr int SQW = 1544;   // qkv row stride (ushorts): 3088B -> 4-bank row step

__device__ __forceinline__ unsigned short f2bf(float f) {
  unsigned u = __float_as_uint(f);
  u += 0x7fff + ((u >> 16) & 1);  // RNE
  return (unsigned short)(u >> 16);
}
__device__ __forceinline__ float bf2f(unsigned short h) {
  return __uint_as_float((unsigned)h << 16);
}

// ---- prep: weights -> bf16 in MFMA fragment order (verified round 5) ----
__global__ __launch_bounds__(256) void prep_weights(
    const float* __restrict__ wq, const float* __restrict__ wk,
    const float* __restrict__ wv, const float* __restrict__ wf,
    unsigned short* __restrict__ ws)
{
  int gid = blockIdx.x * 256 + threadIdx.x;   // 0..262143
  if (gid < 196608) {
    int t = gid >> 11, r = gid & 2047;
    int s = r >> 9, l = (r >> 3) & 63, z = r & 7;
    int met = t >> 3, n = t & 7, m = met >> 2, et = met & 3;
    int fr = l & 15, fg = l >> 4;
    int e = et * 16 + fr, k = s * 32 + fg * 8 + z;
    const float* w = (m == 0) ? wq : (m == 1) ? wk : wv;
    float v = w[n * 8192 + k * 64 + e];
    if (m == 0) v *= SCALE;
    ws[gid] = f2bf(v);
  } else {
    int g2 = gid - 196608;
    int t = g2 >> 10, r = g2 & 1023;
    int s = r >> 9, l = (r >> 3) & 63, z = r & 7;
    int n = t >> 3, et = t & 7;
    int fr = l & 15, fg = l >> 4;
    int eo = et * 16 + fr, k = s * 32 + fg * 8 + z;
    ws[gid] = f2bf(wf[n * 8192 + k * 128 + eo]);
  }
}

// ---- fused kernel: 16 tokens/WG, 512 threads ----
__global__ __launch_bounds__(512, 4) void gc_fused(
    const float* __restrict__ x,
    const unsigned short* __restrict__ wsw,   // 96 qkv tiles [2048]
    const unsigned short* __restrict__ wsf,   // 64 wf tiles  [1024]
    float* __restrict__ out)
{
  // overlays: stage-x rows at r*SXW; after barrier qkv rows at t*SQW
  // per token: q [0,512) | k [512,1024) | v [1024,1536); attn_out overwrites q.
  __shared__ __align__(16) unsigned short smem[16 * SQW];   // 49.4 KB
  __shared__ float spT[16][NH][NB][NB + 1];                 // 9.2 KB

  const int tid  = threadIdx.x;
  const int lane = tid & 63;
  const int w    = tid >> 6;
  const int fr   = lane & 15;
  const int fg   = lane >> 4;
  const long tok0 = (long)blockIdx.x * 16;

  // ---- stage x -> bf16 LDS (coalesced; identical to round 5) ----
  {
    const float* xb = x + tok0 * DIM;
    float4 xa[4], xc[4];
    #pragma unroll
    for (int jj = 0; jj < 4; ++jj) {
      int chunk = tid + 512 * jj;                  // 32B chunks, 128 per token row
      const float* src = xb + (long)(chunk >> 7) * DIM + (chunk & 127) * 8;
      xa[jj] = *reinterpret_cast<const float4*>(src);
      xc[jj] = *reinterpret_cast<const float4*>(src + 4);
    }
    #pragma unroll
    for (int jj = 0; jj < 4; ++jj) {
      int chunk = tid + 512 * jj;
      ushort8 v;
      v[0] = f2bf(xa[jj].x); v[1] = f2bf(xa[jj].y);
      v[2] = f2bf(xa[jj].z); v[3] = f2bf(xa[jj].w);
      v[4] = f2bf(xc[jj].x); v[5] = f2bf(xc[jj].y);
      v[6] = f2bf(xc[jj].z); v[7] = f2bf(xc[jj].w);
      *reinterpret_cast<ushort8*>(&smem[(chunk >> 7) * SXW + (chunk & 127) * 8]) = v;
    }
  }
  __syncthreads();

  // ---- phase A: 96 QKV tiles over 8 waves, dbuf weight prefetch (round 5) ----
  ushort4 qreg[12];
  {
    short8 wfr[2][4];
    const unsigned short* wp0 = wsw + (w * 12) * 2048 + lane * 8;
    #pragma unroll
    for (int s = 0; s < 4; ++s)
      wfr[0][s] = *reinterpret_cast<const short8*>(wp0 + s * 512);
    #pragma unroll
    for (int j = 0; j < 12; ++j) {
      const int cc = w * 12 + j;
      const int n  = cc & 7;
      if (j < 11) {
        const unsigned short* wpn = wsw + (cc + 1) * 2048 + lane * 8;
        #pragma unroll
        for (int s = 0; s < 4; ++s)
          wfr[(j + 1) & 1][s] = *reinterpret_cast<const short8*>(wpn + s * 512);
      }
      short8 bfr[4];
      #pragma unroll
      for (int s = 0; s < 4; ++s)
        bfr[s] = *reinterpret_cast<const short8*>(&smem[fr * SXW + n * 128 + s * 32 + fg * 8]);
      f32x4 acc = {0.f, 0.f, 0.f, 0.f};
      #pragma unroll
      for (int s = 0; s < 4; ++s)
        acc = __builtin_amdgcn_mfma_f32_16x16x32_bf16(wfr[j & 1][s], bfr[s], acc, 0, 0, 0);
      ushort4 d4;
      d4.x = f2bf(acc[0]); d4.y = f2bf(acc[1]);
      d4.z = f2bf(acc[2]); d4.w = f2bf(acc[3]);
      qreg[j] = d4;
    }
  }
  __syncthreads();                                 // x region dies
  {
    #pragma unroll
    for (int j = 0; j < 12; ++j) {
      const int cc = w * 12 + j;
      const int met = cc >> 3, n = cc & 7;
      const int m = met >> 2, e0 = (met & 3) * 16;
      *reinterpret_cast<ushort4*>(&smem[fr * SQW + m * 512 + n * 64 + e0 + fg * 4]) = qreg[j];
    }
  }
  __syncthreads();

  // ---- phase B (NEW, the only change vs round 5): scores via MFMA + xor-16
  // softmax.  Wave w owns tokens t = 2w, 2w+1.  D = mfma(A=K, B=Q):
  // D[row=(h_r,m)][col=(h_c,n)], row = h*8+m via rowoff; softmax over the 8
  // rows of head h_c = pair-reduce across lanes ga<->ga^1 (shfl_xor 16).
  // Cross-head quadrants (ga>>1 != la>>3) are discarded via `useful`.
  {
    const int la = lane & 15, ga = lane >> 4;
    const int rowoff = (la & 7) * 64 + (la >> 3) * 32;
    const bool useful = ((ga >> 1) == (la >> 3));
    #pragma unroll
    for (int tt = 0; tt < 2; ++tt) {
      const int t = w * 2 + tt;
      const unsigned short* tb = &smem[t * SQW];
      short8 kfr = *reinterpret_cast<const short8*>(tb + 512 + rowoff + ga * 8);
      short8 qfr = *reinterpret_cast<const short8*>(tb + rowoff + ga * 8);
      f32x4 zero = {0.f, 0.f, 0.f, 0.f};
      f32x4 s = __builtin_amdgcn_mfma_f32_16x16x32_bf16(kfr, qfr, zero, 0, 0, 0);
      float m4 = fmaxf(fmaxf(s[0], s[1]), fmaxf(s[2], s[3]));
      float mx = fmaxf(m4, __shfl_xor(m4, 16));
      float e0 = __expf(s[0] - mx), e1 = __expf(s[1] - mx);
      float e2 = __expf(s[2] - mx), e3 = __expf(s[3] - mx);
      float sm  = e0 + e1 + e2 + e3;
      float smt = sm + __shfl_xor(sm, 16);
      if (useful) {                                // only matching-head lanes write
        const float inv = 1.f / smt;               // >= 1 element == 1 -> smt >= 1
        const int h = la >> 3, nq = la & 7, m0 = (ga & 1) * 4;
        spT[t][h][m0 + 0][nq] = e0 * inv;
        spT[t][h][m0 + 1][nq] = e1 * inv;
        spT[t][h][m0 + 2][nq] = e2 * inv;
        spT[t][h][m0 + 3][nq] = e3 * inv;
      }
    }
  }
  __syncthreads();                                 // q reads done; P visible

  // ---- phase C: attn_out = P @ V -> overwrite q region (round 5, proven) ----
  if (tid < 256) {
    const int t = tid >> 4;
    const int h = (tid >> 3) & 1;
    const int g = tid & 7;
    float acc[NB][4] = {};
    #pragma unroll
    for (int m = 0; m < NB; ++m) {
      ushort4 vv = *reinterpret_cast<const ushort4*>(
          &smem[t * SQW + 1024 + m * 64 + h * 32 + g * 4]);
      float v0 = bf2f(vv.x), v1 = bf2f(vv.y), v2 = bf2f(vv.z), v3 = bf2f(vv.w);
      const float* pr = spT[t][h][m];
      #pragma unroll
      for (int nn = 0; nn < NB; ++nn) {
        float p = pr[nn];
        acc[nn][0] = fmaf(p, v0, acc[nn][0]);
        acc[nn][1] = fmaf(p, v1, acc[nn][1]);
        acc[nn][2] = fmaf(p, v2, acc[nn][2]);
        acc[nn][3] = fmaf(p, v3, acc[nn][3]);
      }
    }
    #pragma unroll
    for (int nn = 0; nn < NB; ++nn) {
      ushort4 b;
      b.x = f2bf(acc[nn][0]); b.y = f2bf(acc[nn][1]);
      b.z = f2bf(acc[nn][2]); b.w = f2bf(acc[nn][3]);
      *reinterpret_cast<ushort4*>(&smem[t * SQW + nn * 64 + h * 32 + g * 4]) = b;
    }
  }
  __syncthreads();

  // ---- phase D: out = attn_out @ wf; wave w owns block n = w (round 5) ----
  {
    const int n = w;
    short8 bfr[2];
    #pragma unroll
    for (int s = 0; s < 2; ++s)
      bfr[s] = *reinterpret_cast<const short8*>(&smem[fr * SQW + n * 64 + s * 32 + fg * 8]);
    #pragma unroll
    for (int et = 0; et < 8; ++et) {
      const unsigned short* wp = wsf + (n * 8 + et) * 1024 + lane * 8;
      f32x4 acc = {0.f, 0.f, 0.f, 0.f};
      #pragma unroll
      for (int s = 0; s < 2; ++s) {
        short8 af = *reinterpret_cast<const short8*>(wp + s * 512);
        acc = __builtin_amdgcn_mfma_f32_16x16x32_bf16(af, bfr[s], acc, 0, 0, 0);
      }
      float4 o; o.x = acc[0]; o.y = acc[1]; o.z = acc[2]; o.w = acc[3];
      *reinterpret_cast<float4*>(out + (tok0 + fr) * DIM + n * 128 + et * 16 + fg * 4) = o;
    }
  }
}

extern "C" void kernel_launch(void* const* d_in, const int* in_sizes, int n_in,
                              void* d_out, int out_size, void* d_ws, size_t ws_size,
                              hipStream_t stream) {
  const float* x  = (const float*)d_in[0];
  const float* wq = (const float*)d_in[1];
  const float* wk = (const float*)d_in[2];
  const float* wv = (const float*)d_in[3];
  const float* wf = (const float*)d_in[4];
  float* out = (float*)d_out;
  unsigned short* ws = (unsigned short*)d_ws;

  prep_weights<<<dim3(1024), dim3(256), 0, stream>>>(wq, wk, wv, wf, ws);

  const int tokens = in_sizes[0] / DIM;   // 32768
  gc_fused<<<dim3(tokens / 16), dim3(512), 0, stream>>>(x, ws, ws + 196608, out);
}

// Round 9
// 85.385 us; speedup vs baseline: 2.1843x; 1.0331x over previous
//
#include <hip/hip_runtime.h>
#include <math.h>

using short8  = __attribute__((ext_vector_type(8))) short;
using ushort8 = __attribute__((ext_vector_type(8))) unsigned short;
using f32x4   = __attribute__((ext_vector_type(4))) float;

constexpr int DIM = 1024, NB = 8, NH = 2, HD = 32;
constexpr float SCALE = 0.17677669529663687f;  // HD^-0.5, folded into wq at prep
constexpr int SXW = 1032;   // x-tile row stride (ushorts)
constexpr int SQW = 1544;   // qkv row stride (ushorts)

__device__ __forceinline__ unsigned short f2bf(float f) {
  unsigned u = __float_as_uint(f);
  u += 0x7fff + ((u >> 16) & 1);  // RNE
  return (unsigned short)(u >> 16);
}
__device__ __forceinline__ float bf2f(unsigned short h) {
  return __uint_as_float((unsigned)h << 16);
}
__device__ __forceinline__ unsigned pack2bf(float lo, float hi) {
  return (unsigned)f2bf(lo) | ((unsigned)f2bf(hi) << 16);
}

// ---- prep: weights -> bf16 in MFMA fragment order (verified round 5/7) ----
__global__ __launch_bounds__(256) void prep_weights(
    const float* __restrict__ wq, const float* __restrict__ wk,
    const float* __restrict__ wv, const float* __restrict__ wf,
    unsigned short* __restrict__ ws)
{
  int gid = blockIdx.x * 256 + threadIdx.x;   // 0..262143
  if (gid < 196608) {
    int t = gid >> 11, r = gid & 2047;
    int s = r >> 9, l = (r >> 3) & 63, z = r & 7;
    int met = t >> 3, n = t & 7, m = met >> 2, et = met & 3;
    int fr = l & 15, fg = l >> 4;
    int e = et * 16 + fr, k = s * 32 + fg * 8 + z;
    const float* w = (m == 0) ? wq : (m == 1) ? wk : wv;
    float v = w[n * 8192 + k * 64 + e];
    if (m == 0) v *= SCALE;
    ws[gid] = f2bf(v);
  } else {
    int g2 = gid - 196608;
    int t = g2 >> 10, r = g2 & 1023;
    int s = r >> 9, l = (r >> 3) & 63, z = r & 7;
    int n = t >> 3, et = t & 7;
    int fr = l & 15, fg = l >> 4;
    int eo = et * 16 + fr, k = s * 32 + fg * 8 + z;
    ws[gid] = f2bf(wf[n * 8192 + k * 128 + eo]);
  }
}

// ---- fused kernel: 16 tokens/WG, 512 threads, attention fully on MFMA ----
__global__ __launch_bounds__(512, 6) void gc_fused(
    const float* __restrict__ x,
    const unsigned short* __restrict__ wsw,   // 96 qkv tiles [2048]
    const unsigned short* __restrict__ wsf,   // 64 wf tiles  [1024]
    float* __restrict__ out)
{
  // overlays: stage-x rows at r*SXW; after barrier qkv rows at t*SQW.
  // per token row (1536 used of 1544): q/attn_out [0,512) as n*64+h*32+dd |
  // k [512,1024) as 512+n*64+h*32+dd | vT [1024,1536) as 1024+dd*16+(h*8+n).
  __shared__ __align__(16) unsigned short smem[16 * SQW];   // 49408 B -> 3 WG/CU

  const int tid  = threadIdx.x;
  const int lane = tid & 63;
  const int w    = tid >> 6;
  const int fr   = lane & 15;
  const int fg   = lane >> 4;
  const long tok0 = (long)blockIdx.x * 16;

  // ---- stage x -> bf16 LDS (coalesced; proven) ----
  {
    const float* xb = x + tok0 * DIM;
    float4 xa[4], xc[4];
    #pragma unroll
    for (int jj = 0; jj < 4; ++jj) {
      int chunk = tid + 512 * jj;                  // 32B chunks, 128 per token row
      const float* src = xb + (long)(chunk >> 7) * DIM + (chunk & 127) * 8;
      xa[jj] = *reinterpret_cast<const float4*>(src);
      xc[jj] = *reinterpret_cast<const float4*>(src + 4);
    }
    #pragma unroll
    for (int jj = 0; jj < 4; ++jj) {
      int chunk = tid + 512 * jj;
      ushort8 v;
      v[0] = f2bf(xa[jj].x); v[1] = f2bf(xa[jj].y);
      v[2] = f2bf(xa[jj].z); v[3] = f2bf(xa[jj].w);
      v[4] = f2bf(xc[jj].x); v[5] = f2bf(xc[jj].y);
      v[6] = f2bf(xc[jj].z); v[7] = f2bf(xc[jj].w);
      *reinterpret_cast<ushort8*>(&smem[(chunk >> 7) * SXW + (chunk & 127) * 8]) = v;
    }
  }
  __syncthreads();

  // ---- phase A: 96 QKV tiles over 8 waves, dbuf weight prefetch (proven) ----
  ushort4 qreg[12];
  {
    short8 wfr[2][4];
    const unsigned short* wp0 = wsw + (w * 12) * 2048 + lane * 8;
    #pragma unroll
    for (int s = 0; s < 4; ++s)
      wfr[0][s] = *reinterpret_cast<const short8*>(wp0 + s * 512);
    #pragma unroll
    for (int j = 0; j < 12; ++j) {
      const int cc = w * 12 + j;
      const int n  = cc & 7;
      if (j < 11) {
        const unsigned short* wpn = wsw + (cc + 1) * 2048 + lane * 8;
        #pragma unroll
        for (int s = 0; s < 4; ++s)
          wfr[(j + 1) & 1][s] = *reinterpret_cast<const short8*>(wpn + s * 512);
      }
      short8 bfr[4];
      #pragma unroll
      for (int s = 0; s < 4; ++s)
        bfr[s] = *reinterpret_cast<const short8*>(&smem[fr * SXW + n * 128 + s * 32 + fg * 8]);
      f32x4 acc = {0.f, 0.f, 0.f, 0.f};
      #pragma unroll
      for (int s = 0; s < 4; ++s)
        acc = __builtin_amdgcn_mfma_f32_16x16x32_bf16(wfr[j & 1][s], bfr[s], acc, 0, 0, 0);
      ushort4 d4;
      d4.x = f2bf(acc[0]); d4.y = f2bf(acc[1]);
      d4.z = f2bf(acc[2]); d4.w = f2bf(acc[3]);
      qreg[j] = d4;
    }
  }
  __syncthreads();                                 // x region dies

  // ---- write qkv frags; V goes in TRANSPOSED (vT[dd][h*8+n]) for PV b128 reads ----
  {
    #pragma unroll
    for (int j = 0; j < 12; ++j) {
      const int cc = w * 12 + j;
      const int met = cc >> 3, n = cc & 7;
      const int m = met >> 2, e0 = (met & 3) * 16;
      if (m < 2) {
        *reinterpret_cast<ushort4*>(&smem[fr * SQW + m * 512 + n * 64 + e0 + fg * 4]) = qreg[j];
      } else {
        const unsigned short vals[4] = {qreg[j].x, qreg[j].y, qreg[j].z, qreg[j].w};
        #pragma unroll
        for (int r = 0; r < 4; ++r) {
          int e = e0 + fg * 4 + r, dd = e & 31, h = e >> 5;
          smem[fr * SQW + 1024 + dd * 16 + h * 8 + n] = vals[r];
        }
      }
    }
  }
  __syncthreads();

  // ---- phase B': scores (MFMA, proven) + softmax (proven) + PV (MFMA chain) ----
  // Wave w owns tokens t = 2w, 2w+1.  Score D[row=(h_r= i>>3, m= i&7)][col=(h_c,nq)]
  // = mfma(K, Q).  Lane (la,ga) holds rows ga*4+r of col la.  Widening: lane
  // (la,ga) needs B[k=ga*8+j][la] = P rows ga*8..ga*8+7 -> bpermute from lanes
  // (la, 2ga) and (la, 2ga+1); rows>=16 zeroed (kvalid), cross-head zeroed (useful).
  {
    const int la = lane & 15, ga = lane >> 4;
    const int rowoff = (la & 7) * 64 + (la >> 3) * 32;
    const bool useful = ((ga >> 1) == (la >> 3));
    const bool kvalid = (ga < 2);
    const int srcA = (ga * 32 + la) & 63;
    #pragma unroll
    for (int tt = 0; tt < 2; ++tt) {
      const int t = w * 2 + tt;
      const unsigned short* tb = &smem[t * SQW];
      short8 kfr = *reinterpret_cast<const short8*>(tb + 512 + rowoff + ga * 8);
      short8 qfr = *reinterpret_cast<const short8*>(tb + rowoff + ga * 8);
      f32x4 zero = {0.f, 0.f, 0.f, 0.f};
      f32x4 s = __builtin_amdgcn_mfma_f32_16x16x32_bf16(kfr, qfr, zero, 0, 0, 0);
      float m4 = fmaxf(fmaxf(s[0], s[1]), fmaxf(s[2], s[3]));
      float mx = fmaxf(m4, __shfl_xor(m4, 16));
      float e0 = __expf(s[0] - mx), e1 = __expf(s[1] - mx);
      float e2 = __expf(s[2] - mx), e3 = __expf(s[3] - mx);
      float sm  = e0 + e1 + e2 + e3;
      float smt = sm + __shfl_xor(sm, 16);
      float inv = useful ? (1.f / smt) : 0.f;      // smt >= 1 for useful lanes
      unsigned pk01 = pack2bf(e0 * inv, e1 * inv);
      unsigned pk23 = pack2bf(e2 * inv, e3 * inv);
      unsigned b0 = (unsigned)__builtin_amdgcn_ds_bpermute(srcA * 4, (int)pk01);
      unsigned b1 = (unsigned)__builtin_amdgcn_ds_bpermute(srcA * 4, (int)pk23);
      unsigned b2 = (unsigned)__builtin_amdgcn_ds_bpermute(((srcA + 16) & 63) * 4, (int)pk01);
      unsigned b3 = (unsigned)__builtin_amdgcn_ds_bpermute(((srcA + 16) & 63) * 4, (int)pk23);
      union { unsigned u[4]; short8 s8; } pb;
      pb.u[0] = kvalid ? b0 : 0u;  pb.u[1] = kvalid ? b1 : 0u;
      pb.u[2] = kvalid ? b2 : 0u;  pb.u[3] = kvalid ? b3 : 0u;
      #pragma unroll
      for (int dh = 0; dh < 2; ++dh) {
        // A[row=la][k=ga*8+j] = vT[dd=dh*16+la][k]; ga>=2 reads (ga&1) copy:
        // valid finite data, multiplied by B rows 16..31 == 0.
        short8 va = *reinterpret_cast<const short8*>(
            tb + 1024 + (dh * 16 + la) * 16 + (ga & 1) * 8);
        f32x4 o = __builtin_amdgcn_mfma_f32_16x16x32_bf16(va, pb.s8, zero, 0, 0, 0);
        // D[i=ga*4+r][col=la] -> attn_out[n=la&7][h=la>>3][d=dh*16+ga*4+r]
        ushort4 ou;
        ou.x = f2bf(o[0]); ou.y = f2bf(o[1]); ou.z = f2bf(o[2]); ou.w = f2bf(o[3]);
        *reinterpret_cast<ushort4*>(
            &smem[t * SQW + (la & 7) * 64 + (la >> 3) * 32 + dh * 16 + ga * 4]) = ou;
      }
    }
  }
  __syncthreads();

  // ---- phase D: out = attn_out @ wf; wave w owns block n = w (proven) ----
  {
    const int n = w;
    short8 bfr[2];
    #pragma unroll
    for (int s = 0; s < 2; ++s)
      bfr[s] = *reinterpret_cast<const short8*>(&smem[fr * SQW + n * 64 + s * 32 + fg * 8]);
    #pragma unroll
    for (int et = 0; et < 8; ++et) {
      const unsigned short* wp = wsf + (n * 8 + et) * 1024 + lane * 8;
      f32x4 acc = {0.f, 0.f, 0.f, 0.f};
      #pragma unroll
      for (int s = 0; s < 2; ++s) {
        short8 af = *reinterpret_cast<const short8*>(wp + s * 512);
        acc = __builtin_amdgcn_mfma_f32_16x16x32_bf16(af, bfr[s], acc, 0, 0, 0);
      }
      float4 o; o.x = acc[0]; o.y = acc[1]; o.z = acc[2]; o.w = acc[3];
      *reinterpret_cast<float4*>(out + (tok0 + fr) * DIM + n * 128 + et * 16 + fg * 4) = o;
    }
  }
}

extern "C" void kernel_launch(void* const* d_in, const int* in_sizes, int n_in,
                              void* d_out, int out_size, void* d_ws, size_t ws_size,
                              hipStream_t stream) {
  const float* x  = (const float*)d_in[0];
  const float* wq = (const float*)d_in[1];
  const float* wk = (const float*)d_in[2];
  const float* wv = (const float*)d_in[3];
  const float* wf = (const float*)d_in[4];
  float* out = (float*)d_out;
  unsigned short* ws = (unsigned short*)d_ws;

  prep_weights<<<dim3(1024), dim3(256), 0, stream>>>(wq, wk, wv, wf, ws);

  const int tokens = in_sizes[0] / DIM;   // 32768
  gc_fused<<<dim3(tokens / 16), dim3(512), 0, stream>>>(x, ws, ws + 196608, out);
}